// Round 1
// baseline (1152.917 us; speedup 1.0000x reference)
//
#include <hip/hip_runtime.h>

#define TL 1024
#define NT 1023

typedef __bf16 bf16x8 __attribute__((ext_vector_type(8)));
typedef float  f32x4  __attribute__((ext_vector_type(4)));

__device__ __forceinline__ f32x4 mfma_bf16(bf16x8 a, bf16x8 b, f32x4 c) {
  return __builtin_amdgcn_mfma_f32_16x16x32_bf16(a, b, c, 0, 0, 0);
}

// pack bf16(e) into low16, bf16(o) into high16 (truncation)
__device__ __forceinline__ unsigned pk_hi(unsigned e, unsigned o) {
  return __builtin_amdgcn_perm(o, e, 0x07060302u);
}

__device__ __forceinline__ float fast_tanh(float x) {
  float e = __builtin_amdgcn_exp2f(x * 2.8853900817779268f);
  float r = __builtin_amdgcn_rcpf(e + 1.0f);
  return fmaf(-2.0f, r, 1.0f);
}

// split 8 fp32 (k-contiguous) into hi/lo bf16 fragments (truncation + residual)
__device__ __forceinline__ void split8(const float x[8], bf16x8& hi, bf16x8& lo) {
  unsigned h[4], l[4];
#pragma unroll
  for (int j = 0; j < 4; ++j) {
    unsigned eu = __float_as_uint(x[2 * j]);
    unsigned ou = __float_as_uint(x[2 * j + 1]);
    h[j] = pk_hi(eu, ou);
    float el = x[2 * j]     - __uint_as_float(eu & 0xFFFF0000u);
    float ol = x[2 * j + 1] - __uint_as_float(ou & 0xFFFF0000u);
    l[j] = pk_hi(__float_as_uint(el), __float_as_uint(ol));
  }
  hi = __builtin_bit_cast(bf16x8, make_uint4(h[0], h[1], h[2], h[3]));
  lo = __builtin_bit_cast(bf16x8, make_uint4(l[0], l[1], l[2], l[3]));
}

// ---------------------------------------------------------------------------
// One wave (64 threads) per 32 batch elements = TWO independent 16-wide
// groups interleaved at instruction level. With 1 wave/SIMD and a serial
// time scan, the kernel is latency-exposed (counters: ~70% stall); the
// second group's independent chains fill the first group's bubbles.
// Head MFMAs / q-update / store are deferred one step: at step t they
// consume the still-live B-fragments (= state t-1), so the output tail of
// step t-1 executes under step t's recurrent-MFMA + tanh latency.
// ---------------------------------------------------------------------------
__global__ __launch_bounds__(64, 1) void memann_kernel(
    const int* __restrict__ actions, const float* __restrict__ rewards,
    const float* __restrict__ w_r1, const float* __restrict__ b_r1,
    const float* __restrict__ w_r2, const float* __restrict__ b_r2,
    const float* __restrict__ w_a1, const float* __restrict__ b_a1,
    const float* __restrict__ w_a2, const float* __restrict__ b_a2,
    float* __restrict__ out) {
  const int l  = threadIdx.x;       // 0..63
  const int b0 = blockIdx.x * 32;   // batch base for this wave (2 groups)
  const int m  = l & 15;            // A-frag: output-row index
  const int ga = l >> 4;            // A/B-frag: k-group (k = 8*ga + i)
  const int c  = l & 15;            // D-frag: batch column
  const int gD = l >> 4;            // D-frag: row-group (row = 4*gD + reg)

  // ---- one-time: module-A post-add table (bias + one-hot column), pi-rows --
  __shared__ __align__(16) float tbl[2][4][64][4];  // [half][action][lane][reg]
#pragma unroll
  for (int h = 0; h < 2; ++h)
#pragma unroll
    for (int a = 0; a < 4; ++a)
#pragma unroll
      for (int i = 0; i < 4; ++i) {
        const int row = 8 * gD + 4 * h + i;
        tbl[h][a][l][i] = b_a1[row] + w_a1[row * 36 + a];
      }
  __syncthreads();

  // ---- one-time: weight A-fragments (hi/lo split, pi-permuted rows) ----
  const int rowA = 8 * (m >> 2) + (m & 3);  // pi(m, 0)
  float wt[8];
  bf16x8 AWr_h[2], AWr_l[2], AWa_h[2], AWa_l[2], AQ_h, AQ_l, AC_h, AC_l;
#pragma unroll
  for (int h = 0; h < 2; ++h) {
#pragma unroll
    for (int i = 0; i < 8; ++i)
      wt[i] = w_r1[(rowA + 4 * h) * 33 + 1 + 8 * ga + i];
    split8(wt, AWr_h[h], AWr_l[h]);
#pragma unroll
    for (int i = 0; i < 8; ++i)
      wt[i] = w_a1[(rowA + 4 * h) * 36 + 4 + 8 * ga + i];
    split8(wt, AWa_h[h], AWa_l[h]);
  }
#pragma unroll
  for (int i = 0; i < 8; ++i) wt[i] = w_r2[8 * ga + i];   // all 16 rows = wr2
  split8(wt, AQ_h, AQ_l);
#pragma unroll
  for (int i = 0; i < 8; ++i) wt[i] = w_a2[(m & 3) * 32 + 8 * ga + i];
  split8(wt, AC_h, AC_l);

  // ---- one-time: module-R C-init constants (pi-rows) ----
  float br1p[8], wr0p[8];
#pragma unroll
  for (int i = 0; i < 4; ++i) {
    br1p[i]     = b_r1[8 * gD + i];
    wr0p[i]     = w_r1[(8 * gD + i) * 33];
    br1p[4 + i] = b_r1[8 * gD + 4 + i];
    wr0p[4 + i] = w_r1[(8 * gD + 4 + i) * 33];
  }
  const float br2  = b_r2[0];
  const float ba2g = b_a2[gD];

  // ---- per-group input staging / state / output ----
  const int*   arow[2];
  const float* rrow[2];
  int4   a_cur[2], a_nxt[2];
  float4 r_cur[2], r_nxt[2];
  bf16x8 Bsr_h[2], Bsr_l[2], Bsa_h[2], Bsa_l[2];
  float  qv[2];
  int    ap[2];
  float* outp[2];

  const uint4 z4 = make_uint4(0u, 0u, 0u, 0u);
  const f32x4 zero = {0.f, 0.f, 0.f, 0.f};
#pragma unroll
  for (int g = 0; g < 2; ++g) {
    arow[g] = actions + (size_t)(b0 + 16 * g + c) * TL;
    rrow[g] = rewards + (size_t)(b0 + 16 * g + c) * TL;
    a_cur[g] = *(const int4*)(arow[g]);
    r_cur[g] = *(const float4*)(rrow[g]);
    a_nxt[g] = *(const int4*)(arow[g] + 4);
    r_nxt[g] = *(const float4*)(rrow[g] + 4);
    Bsr_h[g] = __builtin_bit_cast(bf16x8, z4);
    Bsr_l[g] = Bsr_h[g];
    Bsa_h[g] = Bsr_h[g];
    Bsa_l[g] = Bsr_h[g];
    qv[g] = 0.0f;
    ap[g] = -1;                       // never matches gD -> t=0 update is 0*0.95
    outp[g] = out + (size_t)(b0 + 16 * g + c) * NT * 4 + gD;
  }

  for (int t0 = 0; t0 < TL; t0 += 4) {
#pragma unroll
    for (int u = 0; u < 4; ++u) {
      const int t = t0 + u;
      int   ag[2];
      float rg[2];
#pragma unroll
      for (int g = 0; g < 2; ++g) {
        ag[g] = (u == 0) ? a_cur[g].x : (u == 1) ? a_cur[g].y
                : (u == 2) ? a_cur[g].z : a_cur[g].w;
        rg[g] = (u == 0) ? r_cur[g].x : (u == 1) ? r_cur[g].y
                : (u == 2) ? r_cur[g].z : r_cur[g].w;
      }

      // --- phase A: LDS table reads (consumed late) + module-R C-init ---
      f32x4 pa0[2], pa1[2], cR0[2], cR1[2];
#pragma unroll
      for (int g = 0; g < 2; ++g) {
        pa0[g] = *(const f32x4*)&tbl[0][ag[g]][l][0];
        pa1[g] = *(const f32x4*)&tbl[1][ag[g]][l][0];
#pragma unroll
        for (int i = 0; i < 4; ++i) {
          cR0[g][i] = fmaf(wr0p[i],     rg[g], br1p[i]);
          cR1[g][i] = fmaf(wr0p[4 + i], rg[g], br1p[4 + i]);
        }
      }

      // --- phase B: recurrent MFMAs, groups interleaved (chains 8 apart) ---
      f32x4 dR0[2], dR1[2], dA0[2], dA1[2];
#pragma unroll
      for (int g = 0; g < 2; ++g) dR0[g] = mfma_bf16(AWr_h[0], Bsr_h[g], cR0[g]);
#pragma unroll
      for (int g = 0; g < 2; ++g) dR1[g] = mfma_bf16(AWr_h[1], Bsr_h[g], cR1[g]);
#pragma unroll
      for (int g = 0; g < 2; ++g) dA0[g] = mfma_bf16(AWa_h[0], Bsa_h[g], zero);
#pragma unroll
      for (int g = 0; g < 2; ++g) dA1[g] = mfma_bf16(AWa_h[1], Bsa_h[g], zero);
#pragma unroll
      for (int g = 0; g < 2; ++g) dR0[g] = mfma_bf16(AWr_h[0], Bsr_l[g], dR0[g]);
#pragma unroll
      for (int g = 0; g < 2; ++g) dR1[g] = mfma_bf16(AWr_h[1], Bsr_l[g], dR1[g]);
#pragma unroll
      for (int g = 0; g < 2; ++g) dA0[g] = mfma_bf16(AWa_h[0], Bsa_l[g], dA0[g]);
#pragma unroll
      for (int g = 0; g < 2; ++g) dA1[g] = mfma_bf16(AWa_h[1], Bsa_l[g], dA1[g]);
#pragma unroll
      for (int g = 0; g < 2; ++g) dR0[g] = mfma_bf16(AWr_l[0], Bsr_h[g], dR0[g]);
#pragma unroll
      for (int g = 0; g < 2; ++g) dR1[g] = mfma_bf16(AWr_l[1], Bsr_h[g], dR1[g]);
#pragma unroll
      for (int g = 0; g < 2; ++g) dA0[g] = mfma_bf16(AWa_l[0], Bsa_h[g], dA0[g]);
#pragma unroll
      for (int g = 0; g < 2; ++g) dA1[g] = mfma_bf16(AWa_l[1], Bsa_h[g], dA1[g]);

      // --- phase C: DEFERRED head MFMAs on the PREVIOUS state (still live
      //     in the B-fragment registers). Results consumed in phase E. ---
      f32x4 dq[2], dc[2];
#pragma unroll
      for (int g = 0; g < 2; ++g) dq[g] = mfma_bf16(AQ_h, Bsr_h[g], zero);
#pragma unroll
      for (int g = 0; g < 2; ++g) dc[g] = mfma_bf16(AC_h, Bsa_h[g], zero);
#pragma unroll
      for (int g = 0; g < 2; ++g) dq[g] = mfma_bf16(AQ_h, Bsr_l[g], dq[g]);
#pragma unroll
      for (int g = 0; g < 2; ++g) dc[g] = mfma_bf16(AC_h, Bsa_l[g], dc[g]);
#pragma unroll
      for (int g = 0; g < 2; ++g) dq[g] = mfma_bf16(AQ_l, Bsr_h[g], dq[g]);
#pragma unroll
      for (int g = 0; g < 2; ++g) dc[g] = mfma_bf16(AC_l, Bsa_h[g], dc[g]);

      // --- phase T: tanh (16 independent chains, groups interleaved) ---
      float xr[2][8], xa[2][8];
#pragma unroll
      for (int i = 0; i < 4; ++i) {
#pragma unroll
        for (int g = 0; g < 2; ++g) {
          xr[g][i]     = fast_tanh(dR0[g][i]);
          xr[g][4 + i] = fast_tanh(dR1[g][i]);
          xa[g][i]     = fast_tanh(dA0[g][i] + pa0[g][i]);
          xa[g][4 + i] = fast_tanh(dA1[g][i] + pa1[g][i]);
        }
      }

      // --- phase E: deferred q-update + store for step t-1 ---
#pragma unroll
      for (int g = 0; g < 2; ++g) {
        const float qn = dq[g][0] + br2;          // q_new of state t-1
        qv[g] = (ap[g] == gD) ? qn : qv[g] * 0.95f;
        const float cs = (gD & 2) ? ((gD & 1) ? dc[g][3] : dc[g][2])
                                  : ((gD & 1) ? dc[g][1] : dc[g][0]);
        const float o = qv[g] + cs + ba2g;
        if (u > 0 || t0 > 0)                      // skip only at t==0
          outp[g][(size_t)(t - 1) * 4] = o;
        ap[g] = ag[g];                            // carry a_t for next step
      }

      // --- phase S: repack new states into next B-fragments ---
#pragma unroll
      for (int g = 0; g < 2; ++g) split8(xr[g], Bsr_h[g], Bsr_l[g]);
#pragma unroll
      for (int g = 0; g < 2; ++g) split8(xa[g], Bsa_h[g], Bsa_l[g]);
    }
    // rotate staging, prefetch next group (clamped; in flight ~4 steps)
    int tp = t0 + 8;
    if (tp > TL - 4) tp = TL - 4;
#pragma unroll
    for (int g = 0; g < 2; ++g) {
      a_cur[g] = a_nxt[g];
      r_cur[g] = r_nxt[g];
      a_nxt[g] = *(const int4*)(arow[g] + tp);
      r_nxt[g] = *(const float4*)(rrow[g] + tp);
    }
  }
}

// ---------- launch ----------

extern "C" void kernel_launch(void* const* d_in, const int* in_sizes, int n_in,
                              void* d_out, int out_size, void* d_ws,
                              size_t ws_size, hipStream_t stream) {
  const int* actions = (const int*)d_in[0];
  const float* rewards = (const float*)d_in[1];
  const float* w_r1 = (const float*)d_in[2];
  const float* b_r1 = (const float*)d_in[3];
  const float* w_r2 = (const float*)d_in[4];
  const float* b_r2 = (const float*)d_in[5];
  const float* w_a1 = (const float*)d_in[6];
  const float* b_a1 = (const float*)d_in[7];
  const float* w_a2 = (const float*)d_in[8];
  const float* b_a2 = (const float*)d_in[9];
  float* out = (float*)d_out;

  const int B = in_sizes[0] / TL;       // 8192
  const int blocks = B / 32;            // 256 waves, one per 32 batch elems

  hipLaunchKernelGGL(memann_kernel, dim3(blocks), dim3(64), 0, stream,
                     actions, rewards, w_r1, b_r1, w_r2, b_r2, w_a1, b_a1,
                     w_a2, b_a2, out);
}

// Round 4
// 678.677 us; speedup vs baseline: 1.6988x; 1.6988x over previous
//
#include <hip/hip_runtime.h>

#define TL 1024
#define NT 1023

typedef __bf16 bf16x8 __attribute__((ext_vector_type(8)));
typedef float  f32x4  __attribute__((ext_vector_type(4)));

__device__ __forceinline__ f32x4 mfma_bf16(bf16x8 a, bf16x8 b, f32x4 c) {
  return __builtin_amdgcn_mfma_f32_16x16x32_bf16(a, b, c, 0, 0, 0);
}

// pack bf16(e) into low16, bf16(o) into high16 (truncation)
__device__ __forceinline__ unsigned pk_hi(unsigned e, unsigned o) {
  return __builtin_amdgcn_perm(o, e, 0x07060302u);
}

__device__ __forceinline__ float fast_tanh(float x) {
  float e = __builtin_amdgcn_exp2f(x * 2.8853900817779268f);
  float r = __builtin_amdgcn_rcpf(e + 1.0f);
  return fmaf(-2.0f, r, 1.0f);
}

// split 8 fp32 (k-contiguous) into hi/lo bf16 fragments (truncation + residual)
__device__ __forceinline__ void split8(const float x[8], bf16x8& hi, bf16x8& lo) {
  unsigned h[4], l[4];
#pragma unroll
  for (int j = 0; j < 4; ++j) {
    unsigned eu = __float_as_uint(x[2 * j]);
    unsigned ou = __float_as_uint(x[2 * j + 1]);
    h[j] = pk_hi(eu, ou);
    float el = x[2 * j]     - __uint_as_float(eu & 0xFFFF0000u);
    float ol = x[2 * j + 1] - __uint_as_float(ou & 0xFFFF0000u);
    l[j] = pk_hi(__float_as_uint(el), __float_as_uint(ol));
  }
  hi = __builtin_bit_cast(bf16x8, make_uint4(h[0], h[1], h[2], h[3]));
  lo = __builtin_bit_cast(bf16x8, make_uint4(l[0], l[1], l[2], l[3]));
}

// ---------------------------------------------------------------------------
// Module split WITHIN one workgroup (no cross-block atomics -- rounds 2/3
// showed cross-XCD fp32 atomic RMW loses updates). Block = 128 threads:
//   wave 0: reward-module recurrence + q head + output assembly/stores
//   wave 1: action-module recurrence + c head -> cs into LDS chunk
// Handoff: double-buffered csb[2][8][64], ONE __syncthreads per 8-step chunk.
//   A writes chunk cI into csb[cI&1] before barrier-cI; R reads it after
//   barrier-cI and before barrier-(cI+1); A reuses csb[cI&1] only after
//   barrier-(cI+1). Race-free with a single barrier per chunk.
// NUMERICS: each module's per-step chain is bit-identical to the verified
// round-0 kernel (rec chain association, tanh, split, head chains, q decay,
// and the left-associated output sum (qv + cs) + ba2g).
// ---------------------------------------------------------------------------
__global__ __launch_bounds__(128, 1) void memann_kernel(
    const int* __restrict__ actions, const float* __restrict__ rewards,
    const float* __restrict__ w_r1, const float* __restrict__ b_r1,
    const float* __restrict__ w_r2, const float* __restrict__ b_r2,
    const float* __restrict__ w_a1, const float* __restrict__ b_a1,
    const float* __restrict__ w_a2, const float* __restrict__ b_a2,
    float* __restrict__ out) {
  const int tid = threadIdx.x;
  const int wid = tid >> 6;         // 0 = reward module, 1 = action module
  const int l   = tid & 63;
  const int b0  = blockIdx.x * 16;  // batch base
  const int m  = l & 15;            // A-frag: output-row index
  const int ga = l >> 4;            // A/B-frag: k-group
  const int c  = l & 15;            // D-frag: batch column
  const int gD = l >> 4;            // D-frag: row-group

  __shared__ __align__(16) float tbl[2][4][64][4];  // [half][action][lane][reg]
  __shared__ __align__(16) float csb[2][8][64];     // [buf][step-in-chunk][lane]

  if (wid == 1) {
#pragma unroll
    for (int h = 0; h < 2; ++h)
#pragma unroll
      for (int a = 0; a < 4; ++a)
#pragma unroll
        for (int i = 0; i < 4; ++i) {
          const int row = 8 * gD + 4 * h + i;
          tbl[h][a][l][i] = b_a1[row] + w_a1[row * 36 + a];
        }
  }
  __syncthreads();

  const uint4 z4 = make_uint4(0u, 0u, 0u, 0u);
  const f32x4 zero = {0.f, 0.f, 0.f, 0.f};
  const int rowA = 8 * (m >> 2) + (m & 3);  // pi(m, 0)
  float wt[8];
  const int* arow = actions + (size_t)(b0 + c) * TL;

  if (wid == 0) {
    // =========== wave 0: reward module + q head + output assembly ===========
    bf16x8 AWr_h[2], AWr_l[2], AQ_h, AQ_l;
#pragma unroll
    for (int h = 0; h < 2; ++h) {
#pragma unroll
      for (int i = 0; i < 8; ++i)
        wt[i] = w_r1[(rowA + 4 * h) * 33 + 1 + 8 * ga + i];
      split8(wt, AWr_h[h], AWr_l[h]);
    }
#pragma unroll
    for (int i = 0; i < 8; ++i) wt[i] = w_r2[8 * ga + i];  // all rows = wr2
    split8(wt, AQ_h, AQ_l);

    float br1p[8], wr0p[8];
#pragma unroll
    for (int i = 0; i < 4; ++i) {
      br1p[i]     = b_r1[8 * gD + i];
      wr0p[i]     = w_r1[(8 * gD + i) * 33];
      br1p[4 + i] = b_r1[8 * gD + 4 + i];
      wr0p[4 + i] = w_r1[(8 * gD + 4 + i) * 33];
    }
    const float br2  = b_r2[0];
    const float ba2g = b_a2[gD];

    const float* rrow = rewards + (size_t)(b0 + c) * TL;
    float* outp = out + (size_t)(b0 + c) * NT * 4 + gD;

    int4   a_cur[2], a_nxt[2];
    float4 r_cur[2], r_nxt[2];
    a_cur[0] = *(const int4*)(arow);
    a_cur[1] = *(const int4*)(arow + 4);
    r_cur[0] = *(const float4*)(rrow);
    r_cur[1] = *(const float4*)(rrow + 4);
    a_nxt[0] = *(const int4*)(arow + 8);
    a_nxt[1] = *(const int4*)(arow + 12);
    r_nxt[0] = *(const float4*)(rrow + 8);
    r_nxt[1] = *(const float4*)(rrow + 12);

    bf16x8 Bh = __builtin_bit_cast(bf16x8, z4), Bl = Bh;
    float qv = 0.0f;
    float qreg[8];

    for (int cI = 0; cI < 128; ++cI) {
#pragma unroll
      for (int j = 0; j < 8; ++j) {
        const int4   av = a_cur[j >> 2];
        const float4 rv = r_cur[j >> 2];
        const int   a  = ((j & 3) == 0) ? av.x : ((j & 3) == 1) ? av.y
                        : ((j & 3) == 2) ? av.z : av.w;
        const float rc = ((j & 3) == 0) ? rv.x : ((j & 3) == 1) ? rv.y
                        : ((j & 3) == 2) ? rv.z : rv.w;

        // C-init: bias + reward column
        f32x4 cR0, cR1;
#pragma unroll
        for (int i = 0; i < 4; ++i) {
          cR0[i] = fmaf(wr0p[i],     rc, br1p[i]);
          cR1[i] = fmaf(wr0p[4 + i], rc, br1p[4 + i]);
        }

        // rec MFMAs: exact round-0 serial association
        f32x4 dR0 = mfma_bf16(AWr_h[0], Bh, cR0);
        f32x4 dR1 = mfma_bf16(AWr_h[1], Bh, cR1);
        dR0 = mfma_bf16(AWr_h[0], Bl, dR0);
        dR1 = mfma_bf16(AWr_h[1], Bl, dR1);
        dR0 = mfma_bf16(AWr_l[0], Bh, dR0);
        dR1 = mfma_bf16(AWr_l[1], Bh, dR1);

        // tanh + repack
        float xr[8];
#pragma unroll
        for (int i = 0; i < 4; ++i) {
          xr[i]     = fast_tanh(dR0[i]);
          xr[4 + i] = fast_tanh(dR1[i]);
        }
        split8(xr, Bh, Bl);

        // q head on the NEW state (exact round-0 chain)
        f32x4 dq = mfma_bf16(AQ_h, Bh, zero);
        dq = mfma_bf16(AQ_h, Bl, dq);
        dq = mfma_bf16(AQ_l, Bh, dq);

        const float qn = dq[0] + br2;
        qv = (a == gD) ? qn : qv * 0.95f;
        qreg[j] = qv;
      }

      __syncthreads();  // A-wave's cs chunk cI is now visible

      const float* cb = &csb[cI & 1][0][0];
#pragma unroll
      for (int j = 0; j < 8; ++j) {
        const int t = 8 * cI + j;
        if (t < NT) outp[(size_t)t * 4] = (qreg[j] + cb[j * 64 + l]) + ba2g;
      }

      // rotate staging, prefetch next chunk (clamped)
      a_cur[0] = a_nxt[0];  a_cur[1] = a_nxt[1];
      r_cur[0] = r_nxt[0];  r_cur[1] = r_nxt[1];
      int tp = 8 * cI + 16;
      if (tp > TL - 8) tp = TL - 8;
      a_nxt[0] = *(const int4*)(arow + tp);
      a_nxt[1] = *(const int4*)(arow + tp + 4);
      r_nxt[0] = *(const float4*)(rrow + tp);
      r_nxt[1] = *(const float4*)(rrow + tp + 4);
    }
  } else {
    // =============== wave 1: action module + c head -> LDS ==================
    bf16x8 AWa_h[2], AWa_l[2], AC_h, AC_l;
#pragma unroll
    for (int h = 0; h < 2; ++h) {
#pragma unroll
      for (int i = 0; i < 8; ++i)
        wt[i] = w_a1[(rowA + 4 * h) * 36 + 4 + 8 * ga + i];
      split8(wt, AWa_h[h], AWa_l[h]);
    }
#pragma unroll
    for (int i = 0; i < 8; ++i) wt[i] = w_a2[(m & 3) * 32 + 8 * ga + i];
    split8(wt, AC_h, AC_l);

    int4 a_cur[2], a_nxt[2];
    a_cur[0] = *(const int4*)(arow);
    a_cur[1] = *(const int4*)(arow + 4);
    a_nxt[0] = *(const int4*)(arow + 8);
    a_nxt[1] = *(const int4*)(arow + 12);

    bf16x8 Bh = __builtin_bit_cast(bf16x8, z4), Bl = Bh;

    for (int cI = 0; cI < 128; ++cI) {
      float* cb = &csb[cI & 1][0][0];
#pragma unroll
      for (int j = 0; j < 8; ++j) {
        const int4 av = a_cur[j >> 2];
        const int  a  = ((j & 3) == 0) ? av.x : ((j & 3) == 1) ? av.y
                       : ((j & 3) == 2) ? av.z : av.w;

        // post-add values (bias + one-hot column) from LDS table
        const f32x4 pa0 = *(const f32x4*)&tbl[0][a][l][0];
        const f32x4 pa1 = *(const f32x4*)&tbl[1][a][l][0];

        // rec MFMAs: exact round-0 serial association
        f32x4 dA0 = mfma_bf16(AWa_h[0], Bh, zero);
        f32x4 dA1 = mfma_bf16(AWa_h[1], Bh, zero);
        dA0 = mfma_bf16(AWa_h[0], Bl, dA0);
        dA1 = mfma_bf16(AWa_h[1], Bl, dA1);
        dA0 = mfma_bf16(AWa_l[0], Bh, dA0);
        dA1 = mfma_bf16(AWa_l[1], Bh, dA1);

        // tanh + repack (exact round-0: tanh(acc + pa))
        float xa[8];
#pragma unroll
        for (int i = 0; i < 4; ++i) {
          xa[i]     = fast_tanh(dA0[i] + pa0[i]);
          xa[4 + i] = fast_tanh(dA1[i] + pa1[i]);
        }
        split8(xa, Bh, Bl);

        // c head on the NEW state (exact round-0 chain)
        f32x4 dc = mfma_bf16(AC_h, Bh, zero);
        dc = mfma_bf16(AC_h, Bl, dc);
        dc = mfma_bf16(AC_l, Bh, dc);

        const float cs = (gD & 2) ? ((gD & 1) ? dc[3] : dc[2])
                                  : ((gD & 1) ? dc[1] : dc[0]);
        cb[j * 64 + l] = cs;
      }

      __syncthreads();  // hand chunk cI to wave 0

      a_cur[0] = a_nxt[0];  a_cur[1] = a_nxt[1];
      int tp = 8 * cI + 16;
      if (tp > TL - 8) tp = TL - 8;
      a_nxt[0] = *(const int4*)(arow + tp);
      a_nxt[1] = *(const int4*)(arow + tp + 4);
    }
  }
}

// ---------- launch ----------

extern "C" void kernel_launch(void* const* d_in, const int* in_sizes, int n_in,
                              void* d_out, int out_size, void* d_ws,
                              size_t ws_size, hipStream_t stream) {
  const int* actions = (const int*)d_in[0];
  const float* rewards = (const float*)d_in[1];
  const float* w_r1 = (const float*)d_in[2];
  const float* b_r1 = (const float*)d_in[3];
  const float* w_r2 = (const float*)d_in[4];
  const float* b_r2 = (const float*)d_in[5];
  const float* w_a1 = (const float*)d_in[6];
  const float* b_a1 = (const float*)d_in[7];
  const float* w_a2 = (const float*)d_in[8];
  const float* b_a2 = (const float*)d_in[9];
  float* out = (float*)d_out;

  const int B = in_sizes[0] / TL;       // 8192
  const int blocks = B / 16;            // 512 blocks x 2 waves (R, A)

  hipLaunchKernelGGL(memann_kernel, dim3(blocks), dim3(128), 0, stream,
                     actions, rewards, w_r1, b_r1, w_r2, b_r2, w_a1, b_a1,
                     w_a2, b_a2, out);
}